// Round 9
// baseline (1039.481 us; speedup 1.0000x reference)
//
#include <hip/hip_runtime.h>
#include <hip/hip_bf16.h>
#include <cstdint>
#include <cstddef>

#define MROWS 100352   // B*H*W = 32*56*56
#define CDIM  512
#define HDIM  2048

typedef __attribute__((ext_vector_type(4))) float floatx4;

// ---- manual f32 -> e4m3fn (OCP), RNE, FTZ below 2^-6, clamp 448 ---------
static __device__ __forceinline__ unsigned int f2fp8(float f) {
  union { float f; unsigned int u; } c; c.f = f;
  const unsigned int u = c.u;
  const unsigned int s = (u >> 24) & 0x80u;
  const unsigned int au = u & 0x7FFFFFFFu;
  if (au < 0x3C800000u) return s;            // |f| < 2^-6 -> +-0 (FTZ)
  if (au > 0x43E00000u) return s | 0x7Eu;    // clamp to 448
  const unsigned int r = au + 0x7FFFFu + ((au >> 20) & 1u);  // RNE at bit 20
  return s | ((r >> 20) - 960u);             // rebias: (127-7)<<3
}

static __device__ __forceinline__ void gload_lds16(const void* g, void* l) {
  __builtin_amdgcn_global_load_lds(
      (const __attribute__((address_space(1))) void*)g,
      (__attribute__((address_space(3))) void*)l, 16, 0, 0);
}

#define BAR()   asm volatile("s_barrier" ::: "memory")
#define LGKM0() asm volatile("s_waitcnt lgkmcnt(0)" ::: "memory")
#define VMC0()  asm volatile("s_waitcnt vmcnt(0)" ::: "memory")

// ---- cast both MLP weight matrices fp32 -> fp8 (x64 scale) --------------
__global__ void cast_weights(const float4* __restrict__ s1, unsigned int* __restrict__ d1,
                             const float4* __restrict__ s2, unsigned int* __restrict__ d2) {
  int t = blockIdx.x * 256 + threadIdx.x;
  const int N4 = (HDIM * CDIM) / 4;
  const float4* s; unsigned int* d; int idx;
  if (t < N4) { s = s1; d = d1; idx = t; }
  else        { s = s2; d = d2; idx = t - N4; }
  float4 f = s[idx];
  d[idx] = f2fp8(f.x * 64.0f) | (f2fp8(f.y * 64.0f) << 8) |
           (f2fp8(f.z * 64.0f) << 16) | (f2fp8(f.w * 64.0f) << 24);
}

// ---- LayerNorm over C=512 + cast to fp8 (x1), one wave per row ----------
__global__ void ln_cast(const float* __restrict__ x, const float* __restrict__ g,
                        const float* __restrict__ b, unsigned int* __restrict__ xn) {
  const int row  = blockIdx.x * 4 + (threadIdx.x >> 6);
  const int lane = threadIdx.x & 63;
  const float4* xr = reinterpret_cast<const float4*>(x + (size_t)row * CDIM);
  const float4 v0 = xr[lane], v1 = xr[lane + 64];
  float s  = v0.x + v0.y + v0.z + v0.w + v1.x + v1.y + v1.z + v1.w;
  float ss = v0.x*v0.x + v0.y*v0.y + v0.z*v0.z + v0.w*v0.w
           + v1.x*v1.x + v1.y*v1.y + v1.z*v1.z + v1.w*v1.w;
#pragma unroll
  for (int o = 1; o < 64; o <<= 1) { s += __shfl_xor(s, o); ss += __shfl_xor(ss, o); }
  const float mean = s * (1.0f / CDIM);
  const float rstd = rsqrtf(ss * (1.0f / CDIM) - mean * mean + 1e-5f);
  const float4* g4 = reinterpret_cast<const float4*>(g);
  const float4* b4 = reinterpret_cast<const float4*>(b);
  const float4 ga = g4[lane], gb = g4[lane + 64];
  const float4 ba = b4[lane], bb = b4[lane + 64];
  const unsigned int p0 =
      f2fp8((v0.x - mean) * rstd * ga.x + ba.x)
    | (f2fp8((v0.y - mean) * rstd * ga.y + ba.y) << 8)
    | (f2fp8((v0.z - mean) * rstd * ga.z + ba.z) << 16)
    | (f2fp8((v0.w - mean) * rstd * ga.w + ba.w) << 24);
  const unsigned int p1 =
      f2fp8((v1.x - mean) * rstd * gb.x + bb.x)
    | (f2fp8((v1.y - mean) * rstd * gb.y + bb.y) << 8)
    | (f2fp8((v1.z - mean) * rstd * gb.z + bb.z) << 16)
    | (f2fp8((v1.w - mean) * rstd * gb.w + bb.w) << 24);
  unsigned int* orow = xn + (size_t)row * (CDIM / 4);
  orow[lane]      = p0;
  orow[lane + 64] = p1;
}

// ---- fp8 GEMM: C = A(MxK) * Bw(NxK)^T, 256x128 tile, dbuf, 2 blk/CU -----
// 512 threads = 8 waves (4M x 2N, wave 64x64), BK=64 (row = 64B -> b64
// frag reads are naturally bank-balanced, no swizzle needed; gload_lds
// dest is linear). LDS 48KB -> with ~90 VGPR: 4 waves/SIMD (2 blocks/CU),
// which is the occupancy that hides the per-K-tile lgkm/vmcnt drains.
// Per K-tile t (buf p): {16 ds_read_b64; stage t+1 -> p^1 (3 gload_lds);
// 32 MFMA fp8 (compiler-counted lgkmcnt overlaps drain); LGKM0 (protect p
// for t+2 staging); VMC0 (t+1 landed, covered by MFMA); BAR}.
// Swapped-operand mfma_f32_16x16x32_fp8_fp8: D[m=lane&15][n=(lane>>4)*4+r].
// Scales: A carries x1 (gemm1) / x8 (G), B carries x64 -> SCI divides out.
// EPI=1: out = fp8(8 * gelu_sigmoid(acc/64 + bias));  EPI=2: f32
// acc/512 + bias + resid.
template<int KDIM, int NDIM, int EPI>
__global__ __launch_bounds__(512, 2) void gemm_fp8(
    const unsigned char* __restrict__ A, const unsigned char* __restrict__ Bw,
    const float* __restrict__ bias, const float* __restrict__ resid,
    void* __restrict__ Cout) {
  constexpr int nt = KDIM / 64;
  __shared__ __align__(16) unsigned char smA[2][256 * 64];   // 16KB/buf
  __shared__ __align__(16) unsigned char smB[2][128 * 64];   // 8KB/buf

  const int tid  = threadIdx.x;
  const int lane = tid & 63, w = tid >> 6;
  const int swr = w >> 1, swc = w & 1;          // wave 4x2 grid, 64x64 tiles
  const int frow = lane & 15, fko = (lane >> 4) * 8;

  // XCD-aware bijective swizzle (grid % 8 == 0 for both launches)
  constexpr int GX = NDIM / 128;
  const int nwg = gridDim.x;
  const int lid = ((int)blockIdx.x & 7) * (nwg >> 3) + ((int)blockIdx.x >> 3);
  const int m0 = (lid / GX) * 256, n0 = (lid % GX) * 128;

  // staging (linear): thread -> row tid>>2 of each 128-row group, 16B chunk
  // tid&3. 512 threads x 16B = 8KB = 128 rows per gload call.
  const int srow = tid >> 2;                    // 0..127
  const int scb  = (tid & 3) * 16;
  const unsigned char* gA = A  + (size_t)(m0 + srow) * KDIM + scb;
  const unsigned char* gB = Bw + (size_t)(n0 + srow) * KDIM + scb;

  auto STG = [&](int t, int buf) {
    const unsigned char* sa = gA + (size_t)t * 64;
    const unsigned char* sb = gB + (size_t)t * 64;
    gload_lds16(sa,                        &smA[buf][tid * 16]);
    gload_lds16(sa + (size_t)128 * KDIM,   &smA[buf][8192 + tid * 16]);
    gload_lds16(sb,                        &smB[buf][tid * 16]);
  };

  floatx4 acc[4][4] = {};   // [mi][nj]

  STG(0, 0);
  VMC0();
  BAR();

  for (int t = 0; t < nt; ++t) {
    const int p = t & 1;
    long a[8], b[8];
#pragma unroll
    for (int mi = 0; mi < 4; ++mi)
#pragma unroll
      for (int kk = 0; kk < 2; ++kk) {
        const int row = swr * 64 + mi * 16 + frow;
        a[mi * 2 + kk] = *reinterpret_cast<const long*>(
            &smA[p][row * 64 + kk * 32 + fko]);
      }
#pragma unroll
    for (int nj = 0; nj < 4; ++nj)
#pragma unroll
      for (int kk = 0; kk < 2; ++kk) {
        const int row = swc * 64 + nj * 16 + frow;
        b[nj * 2 + kk] = *reinterpret_cast<const long*>(
            &smB[p][row * 64 + kk * 32 + fko]);
      }

    if (t + 1 < nt) STG(t + 1, p ^ 1);   // issue early; lands under MFMA

    __builtin_amdgcn_s_setprio(1);
#pragma unroll
    for (int mi = 0; mi < 4; ++mi)
#pragma unroll
      for (int nj = 0; nj < 4; ++nj)
#pragma unroll
        for (int kk = 0; kk < 2; ++kk)   // swapped operands: N -> reg dim
          acc[mi][nj] = __builtin_amdgcn_mfma_f32_16x16x32_fp8_fp8(
              b[nj * 2 + kk], a[mi * 2 + kk], acc[mi][nj], 0, 0, 0);
    __builtin_amdgcn_s_setprio(0);

    if (t + 1 < nt) {
      LGKM0();   // own reads of p done -> safe for t+2 staging into p
      VMC0();    // t+1 fully in LDS
      BAR();     // publish block-wide
    }
  }

  // epilogue (swapped layout): gm = ...+lane&15, gn = ...+(lane>>4)*4 + r
  const int em = lane & 15;
  const int en = (lane >> 4) << 2;
  constexpr float SCI = (EPI == 1) ? (1.0f / 64.0f) : (1.0f / 512.0f);

  float4 bj[4];
#pragma unroll
  for (int nj = 0; nj < 4; ++nj)
    bj[nj] = *reinterpret_cast<const float4*>(&bias[n0 + swc * 64 + nj * 16 + en]);

#pragma unroll
  for (int mi = 0; mi < 4; ++mi) {
    const int gm = m0 + swr * 64 + mi * 16 + em;
    const size_t rowoff = (size_t)gm * NDIM + n0 + swc * 64 + en;
#pragma unroll
    for (int nj = 0; nj < 4; ++nj) {
      const float4 bb = bj[nj];
      const floatx4 av = acc[mi][nj];
      float v0 = av[0] * SCI + bb.x, v1 = av[1] * SCI + bb.y;
      float v2 = av[2] * SCI + bb.z, v3 = av[3] * SCI + bb.w;
      const size_t off = rowoff + nj * 16;
      if (EPI == 1) {
        // gelu ~= v * sigmoid(1.702 v); store fp8(8 * gelu)
        v0 *= 8.0f * __builtin_amdgcn_rcpf(1.0f + __expf(-1.702f * v0));
        v1 *= 8.0f * __builtin_amdgcn_rcpf(1.0f + __expf(-1.702f * v1));
        v2 *= 8.0f * __builtin_amdgcn_rcpf(1.0f + __expf(-1.702f * v2));
        v3 *= 8.0f * __builtin_amdgcn_rcpf(1.0f + __expf(-1.702f * v3));
        *reinterpret_cast<unsigned int*>((unsigned char*)Cout + off) =
            f2fp8(v0) | (f2fp8(v1) << 8) | (f2fp8(v2) << 16) | (f2fp8(v3) << 24);
      } else {
        const float4 r4 = *reinterpret_cast<const float4*>(resid + off);
        float4 o = make_float4(v0 + r4.x, v1 + r4.y, v2 + r4.z, v3 + r4.w);
        *reinterpret_cast<float4*>((float*)Cout + off) = o;
      }
    }
  }
}

extern "C" void kernel_launch(void* const* d_in, const int* in_sizes, int n_in,
                              void* d_out, int out_size, void* d_ws, size_t ws_size,
                              hipStream_t stream) {
  // input order: x wqkv bqkv wo bo g1 b1 g2 b2 w_mlp1 b_mlp1 w_mlp2 b_mlp2
  const float* x   = (const float*)d_in[0];
  const float* g2  = (const float*)d_in[7];
  const float* b2  = (const float*)d_in[8];
  const float* w1  = (const float*)d_in[9];
  const float* b1  = (const float*)d_in[10];
  const float* w2  = (const float*)d_in[11];
  const float* b2m = (const float*)d_in[12];
  float* out = (float*)d_out;

  // Output is exactly x + MLP(LN(x,g2,b2)) — the attention branch of the
  // reference is discarded (xr == x after the two opposite rolls).

  // workspace (fp8): w1b (1MB, x64) | w2b (1MB, x64) | G (205MB, x8)
  unsigned char* w1b = (unsigned char*)d_ws;
  unsigned char* w2b = w1b + (size_t)HDIM * CDIM;
  unsigned char* G   = w2b + (size_t)HDIM * CDIM;
  // LN output (fp8, 51MB) parked in d_out; consumed by GEMM1 before GEMM2
  // overwrites d_out with the final result (stream-ordered).
  unsigned char* xn = (unsigned char*)d_out;

  cast_weights<<<2048, 256, 0, stream>>>(
      (const float4*)w1, (unsigned int*)w1b, (const float4*)w2, (unsigned int*)w2b);
  ln_cast<<<MROWS / 4, 256, 0, stream>>>(x, g2, b2, (unsigned int*)xn);

  // gemm1: (M x 512)*(2048 x 512)^T -> gelu -> fp8 G ; grid 392*16 = 6272
  gemm_fp8<CDIM, HDIM, 1>
      <<<dim3((MROWS / 256) * (HDIM / 128)), 512, 0, stream>>>(
          xn, w1b, b1, nullptr, (void*)G);

  // gemm2: (M x 2048)*(512 x 2048)^T + bias + x -> f32 out ; grid 392*4 = 1568
  gemm_fp8<HDIM, CDIM, 2>
      <<<dim3((MROWS / 256) * (CDIM / 128)), 512, 0, stream>>>(
          G, w2b, b2m, x, (void*)out);
}

// Round 10
// 695.797 us; speedup vs baseline: 1.4939x; 1.4939x over previous
//
#include <hip/hip_runtime.h>
#include <hip/hip_bf16.h>
#include <cstdint>
#include <cstddef>

#define MROWS 100352   // B*H*W = 32*56*56
#define CDIM  512
#define HDIM  2048

typedef __attribute__((ext_vector_type(8))) short   short8;
typedef __attribute__((ext_vector_type(8))) __bf16  bf16x8;
typedef __attribute__((ext_vector_type(4))) __bf16  bf16x4;
typedef __attribute__((ext_vector_type(4))) float   floatx4;

static __device__ __forceinline__ unsigned short f2bf(float f) {
  union { float f; unsigned int u; } c; c.f = f;
  unsigned int u = c.u;
  return (unsigned short)((u + 0x7FFFu + ((u >> 16) & 1u)) >> 16);  // RNE
}

static __device__ __forceinline__ void gload_lds16(const void* g, void* l) {
  __builtin_amdgcn_global_load_lds(
      (const __attribute__((address_space(1))) void*)g,
      (__attribute__((address_space(3))) void*)l, 16, 0, 0);
}

#define BAR()   asm volatile("s_barrier" ::: "memory")
#define VMC0()  asm volatile("s_waitcnt vmcnt(0)" ::: "memory")

// ---- cast both MLP weight matrices fp32 -> bf16 -------------------------
__global__ void cast_weights(const float4* __restrict__ s1, unsigned short* __restrict__ d1,
                             const float4* __restrict__ s2, unsigned short* __restrict__ d2) {
  int t = blockIdx.x * 256 + threadIdx.x;
  const int N4 = (HDIM * CDIM) / 4;
  const float4* s; unsigned short* d; int idx;
  if (t < N4) { s = s1; d = d1; idx = t; }
  else        { s = s2; d = d2; idx = t - N4; }
  float4 f = s[idx];
  ushort4 u = make_ushort4(f2bf(f.x), f2bf(f.y), f2bf(f.z), f2bf(f.w));
  *reinterpret_cast<ushort4*>(d + (size_t)idx * 4) = u;
}

// ---- LayerNorm over C=512 + cast to bf16, one wave per row --------------
__global__ void ln_cast(const float* __restrict__ x, const float* __restrict__ g,
                        const float* __restrict__ b, unsigned short* __restrict__ xn) {
  const int row  = blockIdx.x * 4 + (threadIdx.x >> 6);
  const int lane = threadIdx.x & 63;
  const float4* xr = reinterpret_cast<const float4*>(x + (size_t)row * CDIM);
  const float4 v0 = xr[lane], v1 = xr[lane + 64];
  float s  = v0.x + v0.y + v0.z + v0.w + v1.x + v1.y + v1.z + v1.w;
  float ss = v0.x*v0.x + v0.y*v0.y + v0.z*v0.z + v0.w*v0.w
           + v1.x*v1.x + v1.y*v1.y + v1.z*v1.z + v1.w*v1.w;
#pragma unroll
  for (int o = 1; o < 64; o <<= 1) { s += __shfl_xor(s, o); ss += __shfl_xor(ss, o); }
  const float mean = s * (1.0f / CDIM);
  const float rstd = rsqrtf(ss * (1.0f / CDIM) - mean * mean + 1e-5f);
  const float4* g4 = reinterpret_cast<const float4*>(g);
  const float4* b4 = reinterpret_cast<const float4*>(b);
  const float4 ga = g4[lane], gb = g4[lane + 64];
  const float4 ba = b4[lane], bb = b4[lane + 64];
  ushort4 o0 = make_ushort4(
      f2bf((v0.x - mean) * rstd * ga.x + ba.x),
      f2bf((v0.y - mean) * rstd * ga.y + ba.y),
      f2bf((v0.z - mean) * rstd * ga.z + ba.z),
      f2bf((v0.w - mean) * rstd * ga.w + ba.w));
  ushort4 o1 = make_ushort4(
      f2bf((v1.x - mean) * rstd * gb.x + bb.x),
      f2bf((v1.y - mean) * rstd * gb.y + bb.y),
      f2bf((v1.z - mean) * rstd * gb.z + bb.z),
      f2bf((v1.w - mean) * rstd * gb.w + bb.w));
  unsigned short* orow = xn + (size_t)row * CDIM;
  *reinterpret_cast<ushort4*>(orow + lane * 4)        = o0;
  *reinterpret_cast<ushort4*>(orow + (lane + 64) * 4) = o1;
}

// ---- m97-structure GEMM: 128x128 tile, BK=32, single buffer, 4 blk/CU ---
// C = A(MxK) * Bw(NxK)^T. 256 threads = 4 waves (2x2, wave 64x64).
// LDS 16KB total (A 8KB + B 8KB, SINGLE buffer) -> ~4 blocks/CU (VGPR<=128
// via launch_bounds(256,4)); cross-block wave overlap hides the per-iter
// vmcnt/barrier drains (m97/m114 mechanism: 912 TF at 4096^3, m157).
// Per K-iter (BK=32): {BAR (prev reads done); stage kt (4 gload_lds);
// VMC0; BAR; 8 ds_read_b128 (one per MFMA operand); 16 MFMA}.
// Swizzle: 16B slot s of row r holds source chunk s^(r&3) (pre-swizzled
// global source + same XOR on read) -> 16 lanes/quarter span all 32 banks
// (minimum aliasing; linear layout would be 4x conflicted).
// Swapped-operand mfma_f32_16x16x32_bf16: D[m=lane&15][n=(lane>>4)*4+r]
// -> lane holds 4 consecutive N cols; vectorized epilogue.
// EPI=1: out = bf16(gelu_sigmoid(acc+bias)); EPI=2: f32 acc+bias+resid.
template<int KDIM, int NDIM, int EPI>
__global__ __launch_bounds__(256, 4) void gemm_m97(
    const unsigned short* __restrict__ A, const unsigned short* __restrict__ Bw,
    const float* __restrict__ bias, const float* __restrict__ resid,
    void* __restrict__ Cout) {
  constexpr int nt = KDIM / 32;
  __shared__ __align__(16) unsigned short smA[128 * 32];   // 8KB
  __shared__ __align__(16) unsigned short smB[128 * 32];   // 8KB

  const int tid  = threadIdx.x;
  const int lane = tid & 63, w = tid >> 6;
  const int swr = w >> 1, swc = w & 1;          // wave 2x2 grid, 64x64 tiles
  const int frow = lane & 15, fslot = lane >> 4;   // 16B slot 0..3

  // XCD-aware bijective swizzle (grid % 8 == 0 for both launches);
  // lid is m-major: consecutive lids share the A m-panel -> L2 reuse.
  constexpr int GX = NDIM / 128;
  const int nwg = gridDim.x;
  const int lid = ((int)blockIdx.x & 7) * (nwg >> 3) + ((int)blockIdx.x >> 3);
  const int m0 = (lid / GX) * 128, n0 = (lid % GX) * 128;

  // staging: thread -> row tid>>2 of each 64-row group, 16B chunk tid&3,
  // source chunk pre-swizzled: (tid&3)^((tid>>2)&3)  [rule #21 involution]
  const size_t ldb = (size_t)KDIM * 2;
  const int srow = tid >> 2;                    // 0..63
  const int scb  = ((tid ^ (tid >> 2)) & 3) * 16;
  const char* gA = (const char*)A  + (size_t)(m0 + srow) * ldb + scb;
  const char* gB = (const char*)Bw + (size_t)(n0 + srow) * ldb + scb;

  auto STG = [&](int kt) {
    const char* sa = gA + (size_t)kt * 64;      // kt*32 cols * 2B
    const char* sb = gB + (size_t)kt * 64;
    gload_lds16(sa,                  &smA[tid * 8]);
    gload_lds16(sa + 64 * ldb,       &smA[2048 + tid * 8]);
    gload_lds16(sb,                  &smB[tid * 8]);
    gload_lds16(sb + 64 * ldb,       &smB[2048 + tid * 8]);
  };

  floatx4 acc[4][4] = {};   // [mi][nj]

  for (int kt = 0; kt < nt; ++kt) {
    if (kt > 0) BAR();       // all waves done reading previous tile
    STG(kt);
    VMC0();
    BAR();                   // staged tile visible block-wide

    bf16x8 a[4], b[4];
#pragma unroll
    for (int mi = 0; mi < 4; ++mi) {
      const int row = swr * 64 + mi * 16 + frow;
      const int sl  = fslot ^ (row & 3);
      a[mi] = __builtin_bit_cast(bf16x8,
          *reinterpret_cast<const short8*>(&smA[row * 32 + sl * 8]));
    }
#pragma unroll
    for (int nj = 0; nj < 4; ++nj) {
      const int row = swc * 64 + nj * 16 + frow;
      const int sl  = fslot ^ (row & 3);
      b[nj] = __builtin_bit_cast(bf16x8,
          *reinterpret_cast<const short8*>(&smB[row * 32 + sl * 8]));
    }

    __builtin_amdgcn_s_setprio(1);
#pragma unroll
    for (int mi = 0; mi < 4; ++mi)
#pragma unroll
      for (int nj = 0; nj < 4; ++nj)   // swapped operands: N -> reg dim
        acc[mi][nj] = __builtin_amdgcn_mfma_f32_16x16x32_bf16(
            b[nj], a[mi], acc[mi][nj], 0, 0, 0);
    __builtin_amdgcn_s_setprio(0);
  }

  // epilogue (swapped layout): gm = ...+lane&15, gn = ...+(lane>>4)*4 + r
  const int em = lane & 15;
  const int en = fslot << 2;

  float4 bj[4];
#pragma unroll
  for (int nj = 0; nj < 4; ++nj)
    bj[nj] = *reinterpret_cast<const float4*>(&bias[n0 + swc * 64 + nj * 16 + en]);

#pragma unroll
  for (int mi = 0; mi < 4; ++mi) {
    const int gm = m0 + swr * 64 + mi * 16 + em;
    const size_t rowoff = (size_t)gm * NDIM + n0 + swc * 64 + en;
#pragma unroll
    for (int nj = 0; nj < 4; ++nj) {
      const float4 bb = bj[nj];
      const floatx4 av = acc[mi][nj];
      float v0 = av[0] + bb.x, v1 = av[1] + bb.y;
      float v2 = av[2] + bb.z, v3 = av[3] + bb.w;
      const size_t off = rowoff + nj * 16;
      if (EPI == 1) {
        // gelu ~= v * sigmoid(1.702 v)  (max dev ~0.01, threshold 0.113)
        v0 *= __builtin_amdgcn_rcpf(1.0f + __expf(-1.702f * v0));
        v1 *= __builtin_amdgcn_rcpf(1.0f + __expf(-1.702f * v1));
        v2 *= __builtin_amdgcn_rcpf(1.0f + __expf(-1.702f * v2));
        v3 *= __builtin_amdgcn_rcpf(1.0f + __expf(-1.702f * v3));
        bf16x4 o = { (__bf16)v0, (__bf16)v1, (__bf16)v2, (__bf16)v3 };
        *reinterpret_cast<bf16x4*>((unsigned short*)Cout + off) = o;
      } else {
        const float4 r4 = *reinterpret_cast<const float4*>(resid + off);
        float4 o = make_float4(v0 + r4.x, v1 + r4.y, v2 + r4.z, v3 + r4.w);
        *reinterpret_cast<float4*>((float*)Cout + off) = o;
      }
    }
  }
}

extern "C" void kernel_launch(void* const* d_in, const int* in_sizes, int n_in,
                              void* d_out, int out_size, void* d_ws, size_t ws_size,
                              hipStream_t stream) {
  // input order: x wqkv bqkv wo bo g1 b1 g2 b2 w_mlp1 b_mlp1 w_mlp2 b_mlp2
  const float* x   = (const float*)d_in[0];
  const float* g2  = (const float*)d_in[7];
  const float* b2  = (const float*)d_in[8];
  const float* w1  = (const float*)d_in[9];
  const float* b1  = (const float*)d_in[10];
  const float* w2  = (const float*)d_in[11];
  const float* b2m = (const float*)d_in[12];
  float* out = (float*)d_out;

  // Output is exactly x + MLP(LN(x,g2,b2)) — the attention branch of the
  // reference is discarded (xr == x after the two opposite rolls).

  // workspace: w1b (2MB bf16) | w2b (2MB bf16) | G (411MB bf16)
  unsigned short* w1b = (unsigned short*)d_ws;
  unsigned short* w2b = w1b + (size_t)HDIM * CDIM;
  unsigned short* G   = w2b + (size_t)HDIM * CDIM;
  // LN output (bf16, 103MB) parked in d_out; consumed by GEMM1 before GEMM2
  // overwrites d_out with the final result (stream-ordered).
  unsigned short* xn = (unsigned short*)d_out;

  cast_weights<<<2048, 256, 0, stream>>>((const float4*)w1, w1b, (const float4*)w2, w2b);
  ln_cast<<<MROWS / 4, 256, 0, stream>>>(x, g2, b2, xn);

  // gemm1: (M x 512)*(2048 x 512)^T -> gelu -> bf16 G ; grid 12544 (%8==0)
  gemm_m97<CDIM, HDIM, 1>
      <<<dim3((MROWS / 128) * (HDIM / 128)), 256, 0, stream>>>(
          xn, w1b, b1, nullptr, (void*)G);

  // gemm2: (M x 2048)*(512 x 2048)^T + bias + x -> f32 out ; grid 3136 (%8==0)
  gemm_m97<HDIM, CDIM, 2>
      <<<dim3((MROWS / 128) * (CDIM / 128)), 256, 0, stream>>>(
          G, w2b, b2m, x, (void*)out);
}

// Round 11
// 685.512 us; speedup vs baseline: 1.5164x; 1.0150x over previous
//
#include <hip/hip_runtime.h>
#include <hip/hip_bf16.h>
#include <cstdint>
#include <cstddef>

#define MROWS 100352   // B*H*W = 32*56*56
#define CDIM  512
#define HDIM  2048

typedef __attribute__((ext_vector_type(8))) short   short8;
typedef __attribute__((ext_vector_type(8))) __bf16  bf16x8;
typedef __attribute__((ext_vector_type(4))) __bf16  bf16x4;
typedef __attribute__((ext_vector_type(4))) float   floatx4;

static __device__ __forceinline__ unsigned short f2bf(float f) {
  union { float f; unsigned int u; } c; c.f = f;
  unsigned int u = c.u;
  return (unsigned short)((u + 0x7FFFu + ((u >> 16) & 1u)) >> 16);  // RNE
}

static __device__ __forceinline__ void gload_lds16(const void* g, void* l) {
  __builtin_amdgcn_global_load_lds(
      (const __attribute__((address_space(1))) void*)g,
      (__attribute__((address_space(3))) void*)l, 16, 0, 0);
}

#define BAR()   asm volatile("s_barrier" ::: "memory")
#define LGKM0() asm volatile("s_waitcnt lgkmcnt(0)" ::: "memory")
#define VMC0()  asm volatile("s_waitcnt vmcnt(0)" ::: "memory")

// ---- cast both MLP weight matrices fp32 -> bf16 -------------------------
__global__ void cast_weights(const float4* __restrict__ s1, unsigned short* __restrict__ d1,
                             const float4* __restrict__ s2, unsigned short* __restrict__ d2) {
  int t = blockIdx.x * 256 + threadIdx.x;
  const int N4 = (HDIM * CDIM) / 4;
  const float4* s; unsigned short* d; int idx;
  if (t < N4) { s = s1; d = d1; idx = t; }
  else        { s = s2; d = d2; idx = t - N4; }
  float4 f = s[idx];
  ushort4 u = make_ushort4(f2bf(f.x), f2bf(f.y), f2bf(f.z), f2bf(f.w));
  *reinterpret_cast<ushort4*>(d + (size_t)idx * 4) = u;
}

// ---- LayerNorm over C=512 + cast to bf16, one wave per row --------------
__global__ void ln_cast(const float* __restrict__ x, const float* __restrict__ g,
                        const float* __restrict__ b, unsigned short* __restrict__ xn) {
  const int row  = blockIdx.x * 4 + (threadIdx.x >> 6);
  const int lane = threadIdx.x & 63;
  const float4* xr = reinterpret_cast<const float4*>(x + (size_t)row * CDIM);
  const float4 v0 = xr[lane], v1 = xr[lane + 64];
  float s  = v0.x + v0.y + v0.z + v0.w + v1.x + v1.y + v1.z + v1.w;
  float ss = v0.x*v0.x + v0.y*v0.y + v0.z*v0.z + v0.w*v0.w
           + v1.x*v1.x + v1.y*v1.y + v1.z*v1.z + v1.w*v1.w;
#pragma unroll
  for (int o = 1; o < 64; o <<= 1) { s += __shfl_xor(s, o); ss += __shfl_xor(ss, o); }
  const float mean = s * (1.0f / CDIM);
  const float rstd = rsqrtf(ss * (1.0f / CDIM) - mean * mean + 1e-5f);
  const float4* g4 = reinterpret_cast<const float4*>(g);
  const float4* b4 = reinterpret_cast<const float4*>(b);
  const float4 ga = g4[lane], gb = g4[lane + 64];
  const float4 ba = b4[lane], bb = b4[lane + 64];
  ushort4 o0 = make_ushort4(
      f2bf((v0.x - mean) * rstd * ga.x + ba.x),
      f2bf((v0.y - mean) * rstd * ga.y + ba.y),
      f2bf((v0.z - mean) * rstd * ga.z + ba.z),
      f2bf((v0.w - mean) * rstd * ga.w + ba.w));
  ushort4 o1 = make_ushort4(
      f2bf((v1.x - mean) * rstd * gb.x + bb.x),
      f2bf((v1.y - mean) * rstd * gb.y + bb.y),
      f2bf((v1.z - mean) * rstd * gb.z + bb.z),
      f2bf((v1.w - mean) * rstd * gb.w + bb.w));
  unsigned short* orow = xn + (size_t)row * CDIM;
  *reinterpret_cast<ushort4*>(orow + lane * 4)        = o0;
  *reinterpret_cast<ushort4*>(orow + (lane + 64) * 4) = o1;
}

// ---- m97-structure GEMM: 128x128, BK=32, single buf + overwrite-prefetch
// C = A(MxK) * Bw(NxK)^T. 256 threads = 4 waves (2x2, wave 64x64).
// LDS 16KB single buffer, VGPR ~64 -> ~4 blocks/CU; cross-block overlap
// fills each block's drain windows (m97/m114: 912 TF at 4096^3).
// Per K-iter: {8 ds_read_b128 (frags -> regs); LGKM0+BAR (buffer dead
// block-wide); STG(kt+1) overwrites buffer; 16 MFMA (covers HBM flight);
// VMC0+BAR (next tile landed + published)}.
// Swizzle (corrected): LDS slot s of row r holds source chunk
// s^((r>>1)&3); read slot = fslot^((row>>1)&3). Wave b128 read then hits
// each 16B position with exactly 2 lanes = bank-minimal (free, m136).
// Swapped-operand mfma_f32_16x16x32_bf16: D[m=lane&15][n=(lane>>4)*4+r].
// EPI=1: out = bf16(gelu_sigmoid(acc+bias)); EPI=2: f32 acc+bias+resid.
template<int KDIM, int NDIM, int EPI>
__global__ __launch_bounds__(256, 4) void gemm_m97(
    const unsigned short* __restrict__ A, const unsigned short* __restrict__ Bw,
    const float* __restrict__ bias, const float* __restrict__ resid,
    void* __restrict__ Cout) {
  constexpr int nt = KDIM / 32;
  __shared__ __align__(16) unsigned short smA[128 * 32];   // 8KB
  __shared__ __align__(16) unsigned short smB[128 * 32];   // 8KB

  const int tid  = threadIdx.x;
  const int lane = tid & 63, w = tid >> 6;
  const int swr = w >> 1, swc = w & 1;             // wave 2x2 grid, 64x64
  const int frow = lane & 15, fslot = lane >> 4;   // 16B slot 0..3

  // XCD-aware bijective swizzle (grid % 8 == 0); consecutive lids share
  // the A m-panel -> L2 reuse within an XCD.
  constexpr int GX = NDIM / 128;
  const int nwg = gridDim.x;
  const int lid = ((int)blockIdx.x & 7) * (nwg >> 3) + ((int)blockIdx.x >> 3);
  const int m0 = (lid / GX) * 128, n0 = (lid % GX) * 128;

  // staging: thread -> row tid>>2 of each 64-row group, dest slot tid&3,
  // source chunk (tid&3)^((tid>>3)&3)  [involution with the read XOR]
  const size_t ldb = (size_t)KDIM * 2;
  const int srow = tid >> 2;                       // 0..63
  const int scb  = ((tid ^ (tid >> 3)) & 3) * 16;
  const char* gA = (const char*)A  + (size_t)(m0 + srow) * ldb + scb;
  const char* gB = (const char*)Bw + (size_t)(n0 + srow) * ldb + scb;

  auto STG = [&](int kt) {
    const char* sa = gA + (size_t)kt * 64;         // kt*32 cols * 2B
    const char* sb = gB + (size_t)kt * 64;
    gload_lds16(sa,            &smA[tid * 8]);
    gload_lds16(sa + 64 * ldb, &smA[2048 + tid * 8]);
    gload_lds16(sb,            &smB[tid * 8]);
    gload_lds16(sb + 64 * ldb, &smB[2048 + tid * 8]);
  };

  floatx4 acc[4][4] = {};   // [mi][nj]

  STG(0);
  VMC0();
  BAR();

  for (int kt = 0; kt < nt; ++kt) {
    bf16x8 a[4], b[4];
#pragma unroll
    for (int mi = 0; mi < 4; ++mi) {
      const int row = swr * 64 + mi * 16 + frow;
      const int sl  = fslot ^ ((row >> 1) & 3);
      a[mi] = __builtin_bit_cast(bf16x8,
          *reinterpret_cast<const short8*>(&smA[row * 32 + sl * 8]));
    }
#pragma unroll
    for (int nj = 0; nj < 4; ++nj) {
      const int row = swc * 64 + nj * 16 + frow;
      const int sl  = fslot ^ ((row >> 1) & 3);
      b[nj] = __builtin_bit_cast(bf16x8,
          *reinterpret_cast<const short8*>(&smB[row * 32 + sl * 8]));
    }

    LGKM0();                       // own frags in regs
    BAR();                         // block-wide: buffer fully read -> dead
    if (kt + 1 < nt) STG(kt + 1);  // overwrite; flight covered by MFMA

    __builtin_amdgcn_s_setprio(1);
#pragma unroll
    for (int mi = 0; mi < 4; ++mi)
#pragma unroll
      for (int nj = 0; nj < 4; ++nj)   // swapped operands: N -> reg dim
        acc[mi][nj] = __builtin_amdgcn_mfma_f32_16x16x32_bf16(
            b[nj], a[mi], acc[mi][nj], 0, 0, 0);
    __builtin_amdgcn_s_setprio(0);

    if (kt + 1 < nt) { VMC0(); BAR(); }  // next tile landed + published
  }

  // epilogue (swapped layout): gm = ...+lane&15, gn = ...+(lane>>4)*4 + r
  const int em = lane & 15;
  const int en = fslot << 2;

  float4 bj[4];
#pragma unroll
  for (int nj = 0; nj < 4; ++nj)
    bj[nj] = *reinterpret_cast<const float4*>(&bias[n0 + swc * 64 + nj * 16 + en]);

#pragma unroll
  for (int mi = 0; mi < 4; ++mi) {
    const int gm = m0 + swr * 64 + mi * 16 + em;
    const size_t rowoff = (size_t)gm * NDIM + n0 + swc * 64 + en;
#pragma unroll
    for (int nj = 0; nj < 4; ++nj) {
      const float4 bb = bj[nj];
      const floatx4 av = acc[mi][nj];
      float v0 = av[0] + bb.x, v1 = av[1] + bb.y;
      float v2 = av[2] + bb.z, v3 = av[3] + bb.w;
      const size_t off = rowoff + nj * 16;
      if (EPI == 1) {
        // gelu ~= v * sigmoid(1.702 v)  (max dev ~0.01, threshold 0.113)
        v0 *= __builtin_amdgcn_rcpf(1.0f + __expf(-1.702f * v0));
        v1 *= __builtin_amdgcn_rcpf(1.0f + __expf(-1.702f * v1));
        v2 *= __builtin_amdgcn_rcpf(1.0f + __expf(-1.702f * v2));
        v3 *= __builtin_amdgcn_rcpf(1.0f + __expf(-1.702f * v3));
        bf16x4 o = { (__bf16)v0, (__bf16)v1, (__bf16)v2, (__bf16)v3 };
        *reinterpret_cast<bf16x4*>((unsigned short*)Cout + off) = o;
      } else {
        const float4 r4 = *reinterpret_cast<const float4*>(resid + off);
        float4 o = make_float4(v0 + r4.x, v1 + r4.y, v2 + r4.z, v3 + r4.w);
        *reinterpret_cast<float4*>((float*)Cout + off) = o;
      }
    }
  }
}

extern "C" void kernel_launch(void* const* d_in, const int* in_sizes, int n_in,
                              void* d_out, int out_size, void* d_ws, size_t ws_size,
                              hipStream_t stream) {
  // input order: x wqkv bqkv wo bo g1 b1 g2 b2 w_mlp1 b_mlp1 w_mlp2 b_mlp2
  const float* x   = (const float*)d_in[0];
  const float* g2  = (const float*)d_in[7];
  const float* b2  = (const float*)d_in[8];
  const float* w1  = (const float*)d_in[9];
  const float* b1  = (const float*)d_in[10];
  const float* w2  = (const float*)d_in[11];
  const float* b2m = (const float*)d_in[12];
  float* out = (float*)d_out;

  // Output is exactly x + MLP(LN(x,g2,b2)) — the attention branch of the
  // reference is discarded (xr == x after the two opposite rolls).

  // workspace: w1b (2MB bf16) | w2b (2MB bf16) | G (411MB bf16)
  unsigned short* w1b = (unsigned short*)d_ws;
  unsigned short* w2b = w1b + (size_t)HDIM * CDIM;
  unsigned short* G   = w2b + (size_t)HDIM * CDIM;
  // LN output (bf16, 103MB) parked in d_out; consumed by GEMM1 before GEMM2
  // overwrites d_out with the final result (stream-ordered).
  unsigned short* xn = (unsigned short*)d_out;

  cast_weights<<<2048, 256, 0, stream>>>((const float4*)w1, w1b, (const float4*)w2, w2b);
  ln_cast<<<MROWS / 4, 256, 0, stream>>>(x, g2, b2, xn);

  // gemm1: (M x 512)*(2048 x 512)^T -> gelu -> bf16 G ; grid 12544 (%8==0)
  gemm_m97<CDIM, HDIM, 1>
      <<<dim3((MROWS / 128) * (HDIM / 128)), 256, 0, stream>>>(
          xn, w1b, b1, nullptr, (void*)G);

  // gemm2: (M x 2048)*(512 x 2048)^T + bias + x -> f32 out ; grid 3136 (%8==0)
  gemm_m97<HDIM, CDIM, 2>
      <<<dim3((MROWS / 128) * (CDIM / 128)), 256, 0, stream>>>(
          G, w2b, b2m, x, (void*)out);
}